// Round 8
// baseline (338.201 us; speedup 1.0000x reference)
//
#include <hip/hip_runtime.h>
#include <hip/hip_bf16.h>

// SelfOtherAwareAttention: B=4, L=S=2048, D=256, H=8, hd=32
// qp/kp in workspace: [B*2048][512] bf16, cols 0:256 = self-proj, 256:512 = other-proj
// scale (hd^-0.5) folded into qp.

typedef __attribute__((ext_vector_type(8))) __bf16 bf16x8;
typedef __attribute__((ext_vector_type(4))) float f32x4;
typedef __attribute__((ext_vector_type(4))) int i32x4;
typedef __attribute__((ext_vector_type(4))) unsigned int u32x4;

#define MFMA16(a, b, c) __builtin_amdgcn_mfma_f32_16x16x32_bf16((a), (b), (c), 0, 0, 0)

// LDS-only barrier: waits own LDS ops, then syncs waves — WITHOUT draining the
// global store/load queues (compiler's __syncthreads would emit vmcnt(0) too),
// so output stores stay in flight across phases.
__device__ __forceinline__ void lds_barrier() {
    asm volatile("s_waitcnt lgkmcnt(0)" ::: "memory");
    __builtin_amdgcn_s_barrier();
}

__device__ __forceinline__ bf16x8 load8_f32_to_bf16(const float* __restrict__ p) {
    float4 f0 = *(const float4*)p;
    float4 f1 = *(const float4*)(p + 4);
    bf16x8 r;
    r[0] = (__bf16)f0.x; r[1] = (__bf16)f0.y; r[2] = (__bf16)f0.z; r[3] = (__bf16)f0.w;
    r[4] = (__bf16)f1.x; r[5] = (__bf16)f1.y; r[6] = (__bf16)f1.z; r[7] = (__bf16)f1.w;
    return r;
}

// ---------------- Fused projections: q-side and k-side in one dispatch ----------------
__global__ __launch_bounds__(256) void proj_kernel(
    const float* __restrict__ qin, const float* __restrict__ kin,
    const float* __restrict__ Wqs, const float* __restrict__ Wqo,
    const float* __restrict__ Wks, const float* __restrict__ Wko,
    __bf16* __restrict__ qout, __bf16* __restrict__ kout)
{
    const bool isK = blockIdx.y >= 64;
    const float* in = isK ? kin : qin;
    const float* Ws = isK ? Wks : Wqs;
    const float* Wo = isK ? Wko : Wqo;
    __bf16* outp    = isK ? kout : qout;
    const float scale = isK ? 1.0f : 0.17677669529663687f;  // 32^-0.5

    const int n0 = blockIdx.x * 64;
    const int m0 = (blockIdx.y & 63) * 128;
    const int tid  = threadIdx.x;
    const int lane = tid & 63;
    const int w    = tid >> 6;
    const int wr = w >> 1, wc = w & 1;
    const int l15 = lane & 15, l4 = lane >> 4;

    f32x4 acc[4][2];
#pragma unroll
    for (int mi = 0; mi < 4; ++mi)
#pragma unroll
        for (int ni = 0; ni < 2; ++ni) acc[mi][ni] = (f32x4){0.f, 0.f, 0.f, 0.f};

    const int arow0 = m0 + wr * 64 + l15;  // + mi*16

    const float* wptr[2];
#pragma unroll
    for (int ni = 0; ni < 2; ++ni) {
        int c = n0 + wc * 32 + ni * 16 + l15;
        wptr[ni] = (c < 256) ? (Ws + c * 256) : (Wo + (c - 256) * 256);
    }

#pragma unroll
    for (int ks = 0; ks < 8; ++ks) {
        const int k0 = ks * 32 + l4 * 8;
        bf16x8 a[4], b[2];
#pragma unroll
        for (int mi = 0; mi < 4; ++mi)
            a[mi] = load8_f32_to_bf16(in + (arow0 + mi * 16) * 256 + k0);
#pragma unroll
        for (int ni = 0; ni < 2; ++ni)
            b[ni] = load8_f32_to_bf16(wptr[ni] + k0);
#pragma unroll
        for (int mi = 0; mi < 4; ++mi)
#pragma unroll
            for (int ni = 0; ni < 2; ++ni)
                acc[mi][ni] = MFMA16(a[mi], b[ni], acc[mi][ni]);
    }

    // C/D layout: col = lane&15, row = (lane>>4)*4 + j
#pragma unroll
    for (int mi = 0; mi < 4; ++mi)
#pragma unroll
        for (int ni = 0; ni < 2; ++ni)
#pragma unroll
            for (int j = 0; j < 4; ++j) {
                int row = m0 + wr * 64 + mi * 16 + l4 * 4 + j;
                int col = n0 + wc * 32 + ni * 16 + l15;
                outp[row * 512 + col] = (__bf16)(acc[mi][ni][j] * scale);
            }
}

// ---------------- Fused attention (h-in-grid, s-loop inside, sequential rows) ----------------
// grid (H=8, L/32=64, B=4), x = h FASTEST so the 8 h-blocks of one (b,l-tile) are
// dispatch-adjacent: co-resident across the 8 XCDs, sharing mask/som lines via the
// die-level L3 (mask/som loads are PLAIN, not NT, so they allocate).
// Block = 4 waves; per s-iter (8 x 256 cols) wave w owns 32l x 64s at s-off w*64.
// mfma(A=k_frag, B=q_frag): D col=lane&15 -> l, row=(lane>>4)*4+j -> s.
// Every wave writes its 8 output rows sequentially to completion (1KB per s-iter,
// 8KB total per row) -> fill-like sequential store streams; one block's output is
// one contiguous 256KB range. Barriers are LDS-only so stores drain under compute.
// mask+som are packed into one staged word (som bit in mask LSB: error <= 2^-23 rel).
// NOTE: no min-waves clause in launch_bounds — R7's (256,4) capped VGPR at 128 and
// spilled ~2GB of scratch traffic; uncapped uses ~150 VGPR spill-free, 3 blocks/CU.
__global__ __launch_bounds__(256) void attn_kernel(
    const __bf16* __restrict__ qp, const __bf16* __restrict__ kp,
    const int* __restrict__ som, const float* __restrict__ mask,
    float* __restrict__ out)
{
    __shared__ float tile[32][260];   // stride 260: staging/compute phases conflict-free

    const int h  = blockIdx.x;
    const int l0 = blockIdx.y * 32;
    const int b  = blockIdx.z;
    const int tid  = threadIdx.x;
    const int lane = tid & 63;
    const int w    = tid >> 6;
    const int l15 = lane & 15, l4 = lane >> 4;

    // compute-layout coordinates (block-local): row = l15 + mi*16, col = w*64 + l4*4 + ni*16
    const int c_row = l15;
    const int c_col = w * 64 + l4 * 4;
    const int hofs  = h * 32;

    // q fragments hoisted: rows l0 + l15 + mi*16, head slice h
    bf16x8 qb[2][2];
#pragma unroll
    for (int mi = 0; mi < 2; ++mi)
#pragma unroll
        for (int p = 0; p < 2; ++p)
            qb[mi][p] = *(const bf16x8*)(qp + (long)(b * 2048 + l0 + l15 + mi * 16) * 512
                                            + p * 256 + hofs + l4 * 8);

    const __bf16* kbase = kp + (long)(b * 2048 + w * 64 + l15) * 512 + l4 * 8;

    for (int si = 0; si < 8; ++si) {
        const int s0 = si * 256;

        // k fragments for this s-chunk (issued early; used after mask staging)
        bf16x8 ka[4][2];
#pragma unroll
        for (int ni = 0; ni < 4; ++ni)
#pragma unroll
            for (int p = 0; p < 2; ++p)
                ka[ni][p] = *(const bf16x8*)(kbase + (long)(s0 + ni * 16) * 512
                                                   + p * 256 + hofs);

        // ---- stage packed (mask | som-bit) through LDS: 1KB-coalesced reads ----
#pragma unroll
        for (int i = 0; i < 8; ++i) {
            int r = w * 8 + i;
            long gidx = (long)(b * 2048 + l0 + r) * 2048 + s0 + 4 * lane;
            f32x4 m  = *(const f32x4*)(mask + gidx);
            i32x4 sm = *(const i32x4*)(som + gidx);
            u32x4 pk;
#pragma unroll
            for (int j = 0; j < 4; ++j)
                pk[j] = (__float_as_uint(m[j]) & ~1u) | (sm[j] != 0 ? 1u : 0u);
            *(u32x4*)&tile[r][4 * lane] = pk;
        }
        lds_barrier();

        f32x4 mreg[2][4];
        unsigned int sbits = 0;
#pragma unroll
        for (int mi = 0; mi < 2; ++mi)
#pragma unroll
            for (int ni = 0; ni < 4; ++ni) {
                u32x4 pk = *(const u32x4*)&tile[c_row + mi * 16][c_col + ni * 16];
                const int t0 = (mi * 4 + ni) * 4;
#pragma unroll
                for (int j = 0; j < 4; ++j) {
                    sbits |= (pk[j] & 1u) << (t0 + j);
                    mreg[mi][ni][j] = __uint_as_float(pk[j] & ~1u);
                }
            }
        lds_barrier();

        // ---- compute -> LDS (compute layout) ----
#pragma unroll
        for (int mi = 0; mi < 2; ++mi)
#pragma unroll
            for (int ni = 0; ni < 4; ++ni) {
                f32x4 z = (f32x4){0.f, 0.f, 0.f, 0.f};
                f32x4 as = MFMA16(ka[ni][0], qb[mi][0], z);   // self
                f32x4 ao = MFMA16(ka[ni][1], qb[mi][1], z);   // other
                const int t0 = (mi * 4 + ni) * 4;
                f32x4 v;
#pragma unroll
                for (int j = 0; j < 4; ++j)
                    v[j] = (((sbits >> (t0 + j)) & 1u) ? as[j] : ao[j]) + mreg[mi][ni][j];
                *(f32x4*)&tile[c_row + mi * 16][c_col + ni * 16] = v;
            }
        lds_barrier();

        // ---- store: wave w walks its 8 rows, 1KB contiguous per row per s-iter ----
        const long obase = (long)((b * 8 + h) * 2048 + l0) * 2048 + s0;
#pragma unroll
        for (int i = 0; i < 8; ++i) {
            int r = w * 8 + i;
            f32x4 v = *(const f32x4*)&tile[r][4 * lane];
            *(f32x4*)(out + obase + (long)r * 2048 + 4 * lane) = v;
        }
        lds_barrier();   // own ds_reads done -> tile safe for next s-iter staging
    }
}

extern "C" void kernel_launch(void* const* d_in, const int* in_sizes, int n_in,
                              void* d_out, int out_size, void* d_ws, size_t ws_size,
                              hipStream_t stream) {
    const float* q    = (const float*)d_in[0];
    const float* k    = (const float*)d_in[1];
    const int*   som  = (const int*)d_in[2];
    const float* mask = (const float*)d_in[3];
    const float* Wqs  = (const float*)d_in[4];
    const float* Wqo  = (const float*)d_in[5];
    const float* Wks  = (const float*)d_in[6];
    const float* Wko  = (const float*)d_in[7];
    float* out = (float*)d_out;

    __bf16* qp = (__bf16*)d_ws;            // [8192][512]
    __bf16* kp = qp + 8192 * 512;          // [8192][512]

    dim3 pgrid(8, 128, 1), pblk(256, 1, 1);
    hipLaunchKernelGGL(proj_kernel, pgrid, pblk, 0, stream,
                       q, k, Wqs, Wqo, Wks, Wko, qp, kp);

    dim3 agrid(8, 64, 4), ablk(256, 1, 1);
    hipLaunchKernelGGL(attn_kernel, agrid, ablk, 0, stream, qp, kp, som, mask, out);
}

// Round 9
// 312.684 us; speedup vs baseline: 1.0816x; 1.0816x over previous
//
#include <hip/hip_runtime.h>
#include <hip/hip_bf16.h>

// SelfOtherAwareAttention: B=4, L=S=2048, D=256, H=8, hd=32
// qp/kp in workspace: [B*2048][512] bf16, cols 0:256 = self-proj, 256:512 = other-proj
// scale (hd^-0.5) folded into qp.

typedef __attribute__((ext_vector_type(8))) __bf16 bf16x8;
typedef __attribute__((ext_vector_type(4))) float f32x4;
typedef __attribute__((ext_vector_type(4))) int i32x4;
typedef __attribute__((ext_vector_type(4))) unsigned int u32x4;

#define MFMA16(a, b, c) __builtin_amdgcn_mfma_f32_16x16x32_bf16((a), (b), (c), 0, 0, 0)

// LDS-only barrier: waits own LDS ops, then syncs waves — WITHOUT draining the
// global store/load queues, so output stores stay in flight across phases.
__device__ __forceinline__ void lds_barrier() {
    asm volatile("s_waitcnt lgkmcnt(0)" ::: "memory");
    __builtin_amdgcn_s_barrier();
}

__device__ __forceinline__ bf16x8 load8_f32_to_bf16(const float* __restrict__ p) {
    float4 f0 = *(const float4*)p;
    float4 f1 = *(const float4*)(p + 4);
    bf16x8 r;
    r[0] = (__bf16)f0.x; r[1] = (__bf16)f0.y; r[2] = (__bf16)f0.z; r[3] = (__bf16)f0.w;
    r[4] = (__bf16)f1.x; r[5] = (__bf16)f1.y; r[6] = (__bf16)f1.z; r[7] = (__bf16)f1.w;
    return r;
}

// ---------------- Fused projections: q-side and k-side in one dispatch ----------------
__global__ __launch_bounds__(256) void proj_kernel(
    const float* __restrict__ qin, const float* __restrict__ kin,
    const float* __restrict__ Wqs, const float* __restrict__ Wqo,
    const float* __restrict__ Wks, const float* __restrict__ Wko,
    __bf16* __restrict__ qout, __bf16* __restrict__ kout)
{
    const bool isK = blockIdx.y >= 64;
    const float* in = isK ? kin : qin;
    const float* Ws = isK ? Wks : Wqs;
    const float* Wo = isK ? Wko : Wqo;
    __bf16* outp    = isK ? kout : qout;
    const float scale = isK ? 1.0f : 0.17677669529663687f;  // 32^-0.5

    const int n0 = blockIdx.x * 64;
    const int m0 = (blockIdx.y & 63) * 128;
    const int tid  = threadIdx.x;
    const int lane = tid & 63;
    const int w    = tid >> 6;
    const int wr = w >> 1, wc = w & 1;
    const int l15 = lane & 15, l4 = lane >> 4;

    f32x4 acc[4][2];
#pragma unroll
    for (int mi = 0; mi < 4; ++mi)
#pragma unroll
        for (int ni = 0; ni < 2; ++ni) acc[mi][ni] = (f32x4){0.f, 0.f, 0.f, 0.f};

    const int arow0 = m0 + wr * 64 + l15;  // + mi*16

    const float* wptr[2];
#pragma unroll
    for (int ni = 0; ni < 2; ++ni) {
        int c = n0 + wc * 32 + ni * 16 + l15;
        wptr[ni] = (c < 256) ? (Ws + c * 256) : (Wo + (c - 256) * 256);
    }

#pragma unroll
    for (int ks = 0; ks < 8; ++ks) {
        const int k0 = ks * 32 + l4 * 8;
        bf16x8 a[4], b[2];
#pragma unroll
        for (int mi = 0; mi < 4; ++mi)
            a[mi] = load8_f32_to_bf16(in + (arow0 + mi * 16) * 256 + k0);
#pragma unroll
        for (int ni = 0; ni < 2; ++ni)
            b[ni] = load8_f32_to_bf16(wptr[ni] + k0);
#pragma unroll
        for (int mi = 0; mi < 4; ++mi)
#pragma unroll
            for (int ni = 0; ni < 2; ++ni)
                acc[mi][ni] = MFMA16(a[mi], b[ni], acc[mi][ni]);
    }

    // C/D layout: col = lane&15, row = (lane>>4)*4 + j
#pragma unroll
    for (int mi = 0; mi < 4; ++mi)
#pragma unroll
        for (int ni = 0; ni < 2; ++ni)
#pragma unroll
            for (int j = 0; j < 4; ++j) {
                int row = m0 + wr * 64 + mi * 16 + l4 * 4 + j;
                int col = n0 + wc * 32 + ni * 16 + l15;
                outp[row * 512 + col] = (__bf16)(acc[mi][ni][j] * scale);
            }
}

// ---------------- Fused attention (h-in-grid, XCD-grouped, sequential rows) ----------------
// 1D grid of 2048 blocks. Swizzle (bijective): xcd=n%8, k=n/8, h=k%8, g=k/8,
// p=g*8+xcd, b=p/64, ltile=p%64. All 8 h-blocks of one (b,ltile) share xcd=p%8 and
// are CONSECUTIVE in that XCD's dispatch order -> co-resident; the 512KB mask+som
// slab is HBM-fetched once and served to the other 7 blocks from that XCD's 4MB L2
// (mask/som loads are PLAIN so they allocate).
// Block = 4 waves; per s-iter (8 x 256 cols) wave w owns 32l x 64s at s-off w*64.
// mfma(A=k_frag, B=q_frag): D col=lane&15 -> l, row=(lane>>4)*4+j -> s.
// Every wave writes its 8 output rows sequentially to completion (1KB per s-iter,
// 8KB per row); one block's output = one contiguous 256KB range assembled in L2.
// mask+som packed into one staged word (som bit in mask LSB: error <= 2^-23 rel).
__global__ __launch_bounds__(256) void attn_kernel(
    const __bf16* __restrict__ qp, const __bf16* __restrict__ kp,
    const int* __restrict__ som, const float* __restrict__ mask,
    float* __restrict__ out)
{
    __shared__ float tile[32][260];   // stride 260: all LDS phases at b128 bank floor

    // ---- XCD-grouping swizzle ----
    const int n    = blockIdx.x;
    const int xcd  = n & 7;
    const int kk   = n >> 3;          // 0..255, per-XCD order
    const int h    = kk & 7;
    const int g    = kk >> 3;         // 0..31
    const int p    = g * 8 + xcd;     // (b,ltile) pair 0..255
    const int b    = p >> 6;
    const int l0   = (p & 63) * 32;

    const int tid  = threadIdx.x;
    const int lane = tid & 63;
    const int w    = tid >> 6;
    const int l15 = lane & 15, l4 = lane >> 4;

    // compute-layout coordinates (block-local): row = l15 + mi*16, col = w*64 + l4*4 + ni*16
    const int c_row = l15;
    const int c_col = w * 64 + l4 * 4;
    const int hofs  = h * 32;

    // q fragments hoisted: rows l0 + l15 + mi*16, head slice h
    bf16x8 qb[2][2];
#pragma unroll
    for (int mi = 0; mi < 2; ++mi)
#pragma unroll
        for (int pp = 0; pp < 2; ++pp)
            qb[mi][pp] = *(const bf16x8*)(qp + (long)(b * 2048 + l0 + l15 + mi * 16) * 512
                                             + pp * 256 + hofs + l4 * 8);

    const __bf16* kbase = kp + (long)(b * 2048 + w * 64 + l15) * 512 + l4 * 8;

    for (int si = 0; si < 8; ++si) {
        const int s0 = si * 256;

        // k fragments for this s-chunk
        bf16x8 ka[4][2];
#pragma unroll
        for (int ni = 0; ni < 4; ++ni)
#pragma unroll
            for (int pp = 0; pp < 2; ++pp)
                ka[ni][pp] = *(const bf16x8*)(kbase + (long)(s0 + ni * 16) * 512
                                                    + pp * 256 + hofs);

        // ---- stage packed (mask | som-bit) through LDS: 1KB-coalesced reads ----
#pragma unroll
        for (int i = 0; i < 8; ++i) {
            int r = w * 8 + i;
            long gidx = (long)(b * 2048 + l0 + r) * 2048 + s0 + 4 * lane;
            f32x4 m  = *(const f32x4*)(mask + gidx);
            i32x4 sm = *(const i32x4*)(som + gidx);
            u32x4 pk;
#pragma unroll
            for (int j = 0; j < 4; ++j)
                pk[j] = (__float_as_uint(m[j]) & ~1u) | (sm[j] != 0 ? 1u : 0u);
            *(u32x4*)&tile[r][4 * lane] = pk;
        }
        lds_barrier();

        f32x4 mreg[2][4];
        unsigned int sbits = 0;
#pragma unroll
        for (int mi = 0; mi < 2; ++mi)
#pragma unroll
            for (int ni = 0; ni < 4; ++ni) {
                u32x4 pk = *(const u32x4*)&tile[c_row + mi * 16][c_col + ni * 16];
                const int t0 = (mi * 4 + ni) * 4;
#pragma unroll
                for (int j = 0; j < 4; ++j) {
                    sbits |= (pk[j] & 1u) << (t0 + j);
                    mreg[mi][ni][j] = __uint_as_float(pk[j] & ~1u);
                }
            }
        lds_barrier();

        // ---- compute -> LDS (compute layout) ----
#pragma unroll
        for (int mi = 0; mi < 2; ++mi)
#pragma unroll
            for (int ni = 0; ni < 4; ++ni) {
                f32x4 z = (f32x4){0.f, 0.f, 0.f, 0.f};
                f32x4 as = MFMA16(ka[ni][0], qb[mi][0], z);   // self
                f32x4 ao = MFMA16(ka[ni][1], qb[mi][1], z);   // other
                const int t0 = (mi * 4 + ni) * 4;
                f32x4 v;
#pragma unroll
                for (int j = 0; j < 4; ++j)
                    v[j] = (((sbits >> (t0 + j)) & 1u) ? as[j] : ao[j]) + mreg[mi][ni][j];
                *(f32x4*)&tile[c_row + mi * 16][c_col + ni * 16] = v;
            }
        lds_barrier();

        // ---- store: wave w walks its 8 rows, 1KB contiguous per row per s-iter ----
        const long obase = (long)((b * 8 + h) * 2048 + l0) * 2048 + s0;
#pragma unroll
        for (int i = 0; i < 8; ++i) {
            int r = w * 8 + i;
            f32x4 v = *(const f32x4*)&tile[r][4 * lane];
            *(f32x4*)(out + obase + (long)r * 2048 + 4 * lane) = v;
        }
        lds_barrier();   // own ds_reads done -> tile safe for next s-iter staging
    }
}

extern "C" void kernel_launch(void* const* d_in, const int* in_sizes, int n_in,
                              void* d_out, int out_size, void* d_ws, size_t ws_size,
                              hipStream_t stream) {
    const float* q    = (const float*)d_in[0];
    const float* k    = (const float*)d_in[1];
    const int*   som  = (const int*)d_in[2];
    const float* mask = (const float*)d_in[3];
    const float* Wqs  = (const float*)d_in[4];
    const float* Wqo  = (const float*)d_in[5];
    const float* Wks  = (const float*)d_in[6];
    const float* Wko  = (const float*)d_in[7];
    float* out = (float*)d_out;

    __bf16* qp = (__bf16*)d_ws;            // [8192][512]
    __bf16* kp = qp + 8192 * 512;          // [8192][512]

    dim3 pgrid(8, 128, 1), pblk(256, 1, 1);
    hipLaunchKernelGGL(proj_kernel, pgrid, pblk, 0, stream,
                       q, k, Wqs, Wqo, Wks, Wko, qp, kp);

    dim3 agrid(2048, 1, 1), ablk(256, 1, 1);
    hipLaunchKernelGGL(attn_kernel, agrid, ablk, 0, stream, qp, kp, som, mask, out);
}

// Round 10
// 198.004 us; speedup vs baseline: 1.7081x; 1.5792x over previous
//
#include <hip/hip_runtime.h>
#include <hip/hip_bf16.h>

// SelfOtherAwareAttention: B=4, L=S=2048, D=256, H=8, hd=32
// qp/kp in workspace: [B*2048][512] bf16, cols 0:256 = self-proj, 256:512 = other-proj
// scale (hd^-0.5) folded into qp.
// R10 = R5 (best, 203.7us) + nontemporal output stores (single change).

typedef __attribute__((ext_vector_type(8))) __bf16 bf16x8;
typedef __attribute__((ext_vector_type(4))) float f32x4;
typedef __attribute__((ext_vector_type(4))) int i32x4;

#define MFMA16(a, b, c) __builtin_amdgcn_mfma_f32_16x16x32_bf16((a), (b), (c), 0, 0, 0)

__device__ __forceinline__ bf16x8 load8_f32_to_bf16(const float* __restrict__ p) {
    float4 f0 = *(const float4*)p;
    float4 f1 = *(const float4*)(p + 4);
    bf16x8 r;
    r[0] = (__bf16)f0.x; r[1] = (__bf16)f0.y; r[2] = (__bf16)f0.z; r[3] = (__bf16)f0.w;
    r[4] = (__bf16)f1.x; r[5] = (__bf16)f1.y; r[6] = (__bf16)f1.z; r[7] = (__bf16)f1.w;
    return r;
}

// ---------------- Fused projections: q-side and k-side in one dispatch ----------------
__global__ __launch_bounds__(256) void proj_kernel(
    const float* __restrict__ qin, const float* __restrict__ kin,
    const float* __restrict__ Wqs, const float* __restrict__ Wqo,
    const float* __restrict__ Wks, const float* __restrict__ Wko,
    __bf16* __restrict__ qout, __bf16* __restrict__ kout)
{
    const bool isK = blockIdx.y >= 64;
    const float* in = isK ? kin : qin;
    const float* Ws = isK ? Wks : Wqs;
    const float* Wo = isK ? Wko : Wqo;
    __bf16* outp    = isK ? kout : qout;
    const float scale = isK ? 1.0f : 0.17677669529663687f;  // 32^-0.5

    const int n0 = blockIdx.x * 64;
    const int m0 = (blockIdx.y & 63) * 128;
    const int tid  = threadIdx.x;
    const int lane = tid & 63;
    const int w    = tid >> 6;
    const int wr = w >> 1, wc = w & 1;
    const int l15 = lane & 15, l4 = lane >> 4;

    f32x4 acc[4][2];
#pragma unroll
    for (int mi = 0; mi < 4; ++mi)
#pragma unroll
        for (int ni = 0; ni < 2; ++ni) acc[mi][ni] = (f32x4){0.f, 0.f, 0.f, 0.f};

    const int arow0 = m0 + wr * 64 + l15;  // + mi*16

    const float* wptr[2];
#pragma unroll
    for (int ni = 0; ni < 2; ++ni) {
        int c = n0 + wc * 32 + ni * 16 + l15;
        wptr[ni] = (c < 256) ? (Ws + c * 256) : (Wo + (c - 256) * 256);
    }

#pragma unroll
    for (int ks = 0; ks < 8; ++ks) {
        const int k0 = ks * 32 + l4 * 8;
        bf16x8 a[4], b[2];
#pragma unroll
        for (int mi = 0; mi < 4; ++mi)
            a[mi] = load8_f32_to_bf16(in + (arow0 + mi * 16) * 256 + k0);
#pragma unroll
        for (int ni = 0; ni < 2; ++ni)
            b[ni] = load8_f32_to_bf16(wptr[ni] + k0);
#pragma unroll
        for (int mi = 0; mi < 4; ++mi)
#pragma unroll
            for (int ni = 0; ni < 2; ++ni)
                acc[mi][ni] = MFMA16(a[mi], b[ni], acc[mi][ni]);
    }

    // C/D layout: col = lane&15, row = (lane>>4)*4 + j
#pragma unroll
    for (int mi = 0; mi < 4; ++mi)
#pragma unroll
        for (int ni = 0; ni < 2; ++ni)
#pragma unroll
            for (int j = 0; j < 4; ++j) {
                int row = m0 + wr * 64 + mi * 16 + l4 * 4 + j;
                int col = n0 + wc * 32 + ni * 16 + l15;
                outp[row * 512 + col] = (__bf16)(acc[mi][ni][j] * scale);
            }
}

// ---------------- Fused attention (wide-row tile: 32l x 256s) ----------------
// grid (S/256=8, L/32=64, B=4), block 256 = 4 waves; wave w owns 32l x 64s at
// s-offset w*64. mfma(A=k_frag, B=q_frag): D col=lane&15 -> l, row=(lane>>4)*4+j -> s.
// Epilogue: compute tile -> LDS [32][260] -> stores where ONE wave instruction
// writes ONE full 1KB contiguous row-slice. Mask/som staged through the same LDS
// with 1KB-coalesced global reads.
// R10 change: output stores are NONTEMPORAL (no L2 allocate) so the writeback
// stream reaches DRAM in issue order instead of L2-eviction-shuffled order.
__global__ __launch_bounds__(256) void attn_kernel(
    const __bf16* __restrict__ qp, const __bf16* __restrict__ kp,
    const int* __restrict__ som, const float* __restrict__ mask,
    float* __restrict__ out)
{
    __shared__ float tile[32][260];   // stride 260 floats: both phases at b128 bank floor

    const int s0 = blockIdx.x * 256;
    const int l0 = blockIdx.y * 32;
    const int b  = blockIdx.z;
    const int tid  = threadIdx.x;
    const int lane = tid & 63;
    const int w    = tid >> 6;
    const int l15 = lane & 15, l4 = lane >> 4;

    // compute-layout coordinates (block-local): row = l15 + mi*16, col = w*64 + l4*4 + ni*16
    const int c_row = l15;
    const int c_col = w * 64 + l4 * 4;

    // ---- stage mask, then som, through LDS: coalesced 1KB reads -> compute-layout regs ----
    f32x4 mreg[2][4];
    unsigned int sbits = 0;
#pragma unroll
    for (int i = 0; i < 8; ++i) {
        int r = i * 4 + w;
        f32x4 m = __builtin_nontemporal_load(
            (const f32x4*)(mask + (long)(b * 2048 + l0 + r) * 2048 + s0 + 4 * lane));
        *(f32x4*)&tile[r][4 * lane] = m;
    }
    __syncthreads();
#pragma unroll
    for (int mi = 0; mi < 2; ++mi)
#pragma unroll
        for (int ni = 0; ni < 4; ++ni)
            mreg[mi][ni] = *(const f32x4*)&tile[c_row + mi * 16][c_col + ni * 16];
    __syncthreads();
#pragma unroll
    for (int i = 0; i < 8; ++i) {
        int r = i * 4 + w;
        i32x4 sm = __builtin_nontemporal_load(
            (const i32x4*)(som + (long)(b * 2048 + l0 + r) * 2048 + s0 + 4 * lane));
        *(i32x4*)&tile[r][4 * lane] = sm;
    }
    __syncthreads();
#pragma unroll
    for (int mi = 0; mi < 2; ++mi)
#pragma unroll
        for (int ni = 0; ni < 4; ++ni) {
            i32x4 sm = *(const i32x4*)&tile[c_row + mi * 16][c_col + ni * 16];
            const int t0 = (mi * 4 + ni) * 4;
#pragma unroll
            for (int j = 0; j < 4; ++j)
                sbits |= (sm[j] != 0) ? (1u << (t0 + j)) : 0u;
        }
    __syncthreads();

    // fragment bases: q rows = l (l0 + l15 + mi*16), k rows = s (s0 + w*64 + l15 + ni*16)
    const __bf16* qbase = qp + (long)(b * 2048 + l0 + l15) * 512 + l4 * 8;
    const __bf16* kbase = kp + (long)(b * 2048 + s0 + w * 64 + l15) * 512 + l4 * 8;

    for (int h = 0; h < 8; ++h) {
        const int hofs = h * 32;
        bf16x8 qb[2][2], ka[4][2];
#pragma unroll
        for (int mi = 0; mi < 2; ++mi)
#pragma unroll
            for (int p = 0; p < 2; ++p)
                qb[mi][p] = *(const bf16x8*)(qbase + mi * 16 * 512 + p * 256 + hofs);
#pragma unroll
        for (int ni = 0; ni < 4; ++ni)
#pragma unroll
            for (int p = 0; p < 2; ++p)
                ka[ni][p] = *(const bf16x8*)(kbase + ni * 16 * 512 + p * 256 + hofs);

        // compute -> LDS (compute layout)
#pragma unroll
        for (int mi = 0; mi < 2; ++mi)
#pragma unroll
            for (int ni = 0; ni < 4; ++ni) {
                f32x4 z = (f32x4){0.f, 0.f, 0.f, 0.f};
                f32x4 as = MFMA16(ka[ni][0], qb[mi][0], z);   // self
                f32x4 ao = MFMA16(ka[ni][1], qb[mi][1], z);   // other
                const int t0 = (mi * 4 + ni) * 4;
                f32x4 v;
#pragma unroll
                for (int j = 0; j < 4; ++j)
                    v[j] = (((sbits >> (t0 + j)) & 1u) ? as[j] : ao[j]) + mreg[mi][ni][j];
                *(f32x4*)&tile[c_row + mi * 16][c_col + ni * 16] = v;
            }

        __syncthreads();

        // store: one wave instruction = one full 1KB contiguous row-slice (NT)
        const long obase = (long)((b * 8 + h) * 2048 + l0) * 2048 + s0;
#pragma unroll
        for (int i = 0; i < 8; ++i) {
            int r = i * 4 + w;
            f32x4 v = *(const f32x4*)&tile[r][4 * lane];
            __builtin_nontemporal_store(v, (f32x4*)(out + obase + (long)r * 2048 + 4 * lane));
        }

        __syncthreads();
    }
}

extern "C" void kernel_launch(void* const* d_in, const int* in_sizes, int n_in,
                              void* d_out, int out_size, void* d_ws, size_t ws_size,
                              hipStream_t stream) {
    const float* q    = (const float*)d_in[0];
    const float* k    = (const float*)d_in[1];
    const int*   som  = (const int*)d_in[2];
    const float* mask = (const float*)d_in[3];
    const float* Wqs  = (const float*)d_in[4];
    const float* Wqo  = (const float*)d_in[5];
    const float* Wks  = (const float*)d_in[6];
    const float* Wko  = (const float*)d_in[7];
    float* out = (float*)d_out;

    __bf16* qp = (__bf16*)d_ws;            // [8192][512]
    __bf16* kp = qp + 8192 * 512;          // [8192][512]

    dim3 pgrid(8, 128, 1), pblk(256, 1, 1);
    hipLaunchKernelGGL(proj_kernel, pgrid, pblk, 0, stream,
                       q, k, Wqs, Wqo, Wks, Wko, qp, kp);

    dim3 agrid(8, 64, 4), ablk(256, 1, 1);
    hipLaunchKernelGGL(attn_kernel, agrid, ablk, 0, stream, qp, kp, som, mask, out);
}